// Round 2
// baseline (185.594 us; speedup 1.0000x reference)
//
#include <hip/hip_runtime.h>
#include <math.h>

#define SEQ   576     // H*W = 24*24
#define CDIM  96
#define INNER 192
#define NHEAD 48
#define DH    4
#define NB    2
#define EPSV  1e-5f
#define RT    64      // mlstm row-tile

__device__ __forceinline__ float silu_f(float x) { return x / (1.f + __expf(-x)); }
__device__ __forceinline__ float logsig_f(float x) {
    return (x >= 0.f) ? -log1pf(__expf(-x)) : (x - log1pf(__expf(x)));
}

// ---------------- Kernel A: LayerNorm + up-projection (96 -> 384) ----------------
__global__ void k_ln_up(const float* __restrict__ x, const float* __restrict__ ln_g,
                        const float* __restrict__ ln_b, const float* __restrict__ w_up,
                        const float* __restrict__ b_up,
                        float* __restrict__ xm, float* __restrict__ z) {
    const int bs = blockIdx.x;
    const int b = bs / SEQ, s = bs % SEQ;
    const int t = threadIdx.x;                 // 128 threads
    __shared__ float red[128];
    __shared__ float hbuf[CDIM];

    float val = 0.f;
    if (t < CDIM) val = x[(size_t)(b * CDIM + t) * SEQ + s];
    red[t] = val;
    __syncthreads();
    for (int off = 64; off > 0; off >>= 1) { if (t < off) red[t] += red[t + off]; __syncthreads(); }
    const float mean = red[0] * (1.f / CDIM);
    __syncthreads();
    float d = (t < CDIM) ? (val - mean) : 0.f;
    red[t] = d * d;
    __syncthreads();
    for (int off = 64; off > 0; off >>= 1) { if (t < off) red[t] += red[t + off]; __syncthreads(); }
    const float rstd = rsqrtf(red[0] * (1.f / CDIM) + EPSV);
    if (t < CDIM) hbuf[t] = (val - mean) * rstd * ln_g[t] + ln_b[t];
    __syncthreads();

    for (int f = t; f < 2 * INNER; f += 128) {
        float acc = b_up[f];
        const float* wr = w_up + (size_t)f * CDIM;
        #pragma unroll 8
        for (int c = 0; c < CDIM; ++c) acc += hbuf[c] * wr[c];
        if (f < INNER) xm[(size_t)(b * SEQ + s) * INNER + f] = acc;
        else           z [(size_t)(b * SEQ + s) * INNER + (f - INNER)] = acc;
    }
}

// ------------- Kernel B: causal conv + SiLU, headwise q/k/v, ig/fg gates -------------
__global__ void k_conv_qkv_gates(const float* __restrict__ xm,
    const float* __restrict__ w_conv, const float* __restrict__ b_conv,
    const float* __restrict__ w_q, const float* __restrict__ b_q,
    const float* __restrict__ w_k, const float* __restrict__ b_k,
    const float* __restrict__ w_v, const float* __restrict__ b_v,
    const float* __restrict__ w_ig, const float* __restrict__ b_ig,
    const float* __restrict__ w_fg, const float* __restrict__ b_fg,
    float* __restrict__ xc, float* __restrict__ qw, float* __restrict__ kw,
    float* __restrict__ vw, float* __restrict__ igw, float* __restrict__ fgw) {
    const int bs = blockIdx.x;
    const int b = bs / SEQ, s = bs % SEQ;
    const int t = threadIdx.x;   // 192 threads
    __shared__ float xc_l[INNER], xm_l[INNER], qkv_l[3 * INNER];

    {
        float acc = b_conv[t];
        #pragma unroll
        for (int j = 0; j < 4; ++j) {
            int ss = s - 3 + j;
            if (ss >= 0) acc += xm[(size_t)(b * SEQ + ss) * INNER + t] * w_conv[t * 4 + j];
        }
        float v = silu_f(acc);
        xc_l[t] = v;
        xc[(size_t)(b * SEQ + s) * INNER + t] = v;
        xm_l[t] = xm[(size_t)(b * SEQ + s) * INNER + t];
    }
    __syncthreads();
    {
        const int n = t >> 2, o = t & 3;
        const float* wq = w_q + n * 16 + o * 4;
        const float* wk = w_k + n * 16 + o * 4;
        const float* wv = w_v + n * 16 + o * 4;
        float q = b_q[t], k = b_k[t], v = b_v[t];
        #pragma unroll
        for (int dd = 0; dd < 4; ++dd) {
            q += xc_l[n * 4 + dd] * wq[dd];
            k += xc_l[n * 4 + dd] * wk[dd];
            v += xm_l[n * 4 + dd] * wv[dd];
        }
        qkv_l[t] = q; qkv_l[INNER + t] = k; qkv_l[2 * INNER + t] = v;
        size_t base = ((size_t)(b * NHEAD + n) * SEQ + s) * DH + o;
        qw[base] = q; kw[base] = k; vw[base] = v;
    }
    __syncthreads();
    // ig/fg gates: 2 threads per gate, 96 gates -> all 192 threads active
    {
        const int g = t >> 1, half = t & 1;          // g in [0,96)
        const int h = g % NHEAD;
        const bool isfg = (g >= NHEAD);
        const float* w = (isfg ? w_fg : w_ig) + (size_t)h * 3 * INNER;
        float acc = 0.f;
        for (int f = half; f < 3 * INNER; f += 2) acc += qkv_l[f] * w[f];
        acc += __shfl_xor(acc, 1);
        if (half == 0) {
            acc += isfg ? b_fg[h] : b_ig[h];
            (isfg ? fgw : igw)[(size_t)(b * NHEAD + h) * SEQ + s] = acc;
        }
    }
}

// ------------- Kernel C0: per-head sequence scans (lf_cum, m, prefix-max M) -------------
__global__ void k_scan(const float* __restrict__ igw, const float* __restrict__ fgw,
                       float* __restrict__ m_g, float* __restrict__ M_g,
                       float* __restrict__ lfc_g) {
    const int bh = blockIdx.x;   // 96 blocks
    const int t = threadIdx.x;   // 64 threads (one wave)
    const int base = t * 9;
    float pre[9], mv[9], mx[9];
    float run = 0.f;
    #pragma unroll
    for (int j = 0; j < 9; ++j) {
        run += logsig_f(fgw[(size_t)bh * SEQ + base + j]);
        pre[j] = run;
    }
    float incl = run;
    #pragma unroll
    for (int off = 1; off < 64; off <<= 1) {
        float o = __shfl_up(incl, off);
        if (t >= off) incl += o;
    }
    const float excl = incl - run;
    float runm = -INFINITY;
    #pragma unroll
    for (int j = 0; j < 9; ++j) {
        float lfc = excl + pre[j];                    // lf_cum[t+1]
        lfc_g[(size_t)bh * SEQ + base + j] = lfc;
        float mt = igw[(size_t)bh * SEQ + base + j] - lfc;
        mv[j] = mt;
        runm = fmaxf(runm, mt);
        mx[j] = runm;
    }
    float sc = runm;
    #pragma unroll
    for (int off = 1; off < 64; off <<= 1) {
        float o = __shfl_up(sc, off);
        if (t >= off) sc = fmaxf(sc, o);
    }
    float exclm = __shfl_up(sc, 1);
    if (t == 0) exclm = -INFINITY;
    #pragma unroll
    for (int j = 0; j < 9; ++j) {
        m_g[(size_t)bh * SEQ + base + j] = mv[j];
        M_g[(size_t)bh * SEQ + base + j] = fmaxf(exclm, mx[j]);
    }
}

// ------------- Kernel C: mLSTM, tiled rows, 4 lanes per row -------------
// Dm[s,t] = exp(m[t] - M[s]); max_log_D[s] = lf_cum[s+1] + M[s]
__global__ void __launch_bounds__(256) k_mlstm(const float* __restrict__ qw,
    const float* __restrict__ kw, const float* __restrict__ vw,
    const float* __restrict__ m_g, const float* __restrict__ M_g,
    const float* __restrict__ lfc_g, float* __restrict__ ht) {
    const int bh = blockIdx.x;          // 96
    const int r0 = blockIdx.y * RT;     // 9 tiles of 64 rows
    const int nt = r0 + RT;             // columns needed: [0, nt)
    const int t = threadIdx.x;          // 256 threads = 64 rows x 4 lanes
    __shared__ float4 k4[SEQ], v4[SEQ];
    __shared__ float m_l[SEQ];

    const float4* kb = (const float4*)(kw + (size_t)bh * SEQ * DH);
    const float4* vb = (const float4*)(vw + (size_t)bh * SEQ * DH);
    for (int i = t; i < nt; i += 256) {
        k4[i] = kb[i]; v4[i] = vb[i];
        m_l[i] = m_g[(size_t)bh * SEQ + i];
    }
    __syncthreads();

    const int sub = t & 3;
    const int s0 = r0 + (t >> 2);
    const float4 q = ((const float4*)(qw + (size_t)bh * SEQ * DH))[s0];
    const float Ms = M_g[(size_t)bh * SEQ + s0];
    const float lfcs = lfc_g[(size_t)bh * SEQ + s0];

    float a0 = 0.f, a1 = 0.f, a2 = 0.f, a3 = 0.f, csum = 0.f;
    for (int tt = sub; tt <= s0; tt += 4) {
        float e = __expf(m_l[tt] - Ms);
        float4 kk = k4[tt], vv = v4[tt];
        float qk = q.x * kk.x + q.y * kk.y + q.z * kk.z + q.w * kk.w;
        float c = qk * 0.5f * e;                       // DH^-0.5 = 0.5
        csum += c;
        a0 += c * vv.x; a1 += c * vv.y; a2 += c * vv.z; a3 += c * vv.w;
    }
    #pragma unroll
    for (int off = 1; off < 4; off <<= 1) {
        csum += __shfl_xor(csum, off);
        a0 += __shfl_xor(a0, off); a1 += __shfl_xor(a1, off);
        a2 += __shfl_xor(a2, off); a3 += __shfl_xor(a3, off);
    }
    const float floorv = __expf(-(lfcs + Ms));
    const float inv = 1.f / (fmaxf(fabsf(csum), floorv) + 1e-6f);
    const float val = (sub == 0) ? a0 : (sub == 1) ? a1 : (sub == 2) ? a2 : a3;
    ht[((size_t)bh * SEQ + s0) * 4 + sub] = val * inv;
}

// ------------- Kernel D: per-head LN, skip, z-gate, down-proj, residual -------------
__global__ void k_epilogue(const float* __restrict__ ht, const float* __restrict__ on_g,
    const float* __restrict__ on_b, const float* __restrict__ skip,
    const float* __restrict__ xc, const float* __restrict__ z,
    const float* __restrict__ w_down, const float* __restrict__ b_down,
    const float* __restrict__ x, float* __restrict__ out) {
    const int bs = blockIdx.x;
    const int b = bs / SEQ, s = bs % SEQ;
    const int t = threadIdx.x;   // 192 threads
    __shared__ float ht_l[INNER], hs_l[INNER];
    const int n = t >> 2;

    ht_l[t] = ht[((size_t)(b * NHEAD + n) * SEQ + s) * DH + (t & 3)];
    __syncthreads();
    const float h0 = ht_l[n * 4], h1 = ht_l[n * 4 + 1], h2 = ht_l[n * 4 + 2], h3 = ht_l[n * 4 + 3];
    const float mean = (h0 + h1 + h2 + h3) * 0.25f;
    const float d0 = h0 - mean, d1 = h1 - mean, d2 = h2 - mean, d3 = h3 - mean;
    const float var = (d0 * d0 + d1 * d1 + d2 * d2 + d3 * d3) * 0.25f;
    const float rstd = rsqrtf(var + EPSV);
    const float hn = (ht_l[t] - mean) * rstd * on_g[t] + on_b[t];
    const float hskip = hn + skip[t] * xc[(size_t)(b * SEQ + s) * INNER + t];
    const float zv = z[(size_t)(b * SEQ + s) * INNER + t];
    hs_l[t] = hskip * silu_f(zv);
    __syncthreads();

    if (t < CDIM) {
        float acc = b_down[t];
        const float* wr = w_down + (size_t)t * INNER;
        #pragma unroll 8
        for (int d = 0; d < INNER; ++d) acc += hs_l[d] * wr[d];
        size_t idx = ((size_t)b * CDIM + t) * SEQ + s;
        out[idx] = x[idx] + acc;
    }
}

extern "C" void kernel_launch(void* const* d_in, const int* in_sizes, int n_in,
                              void* d_out, int out_size, void* d_ws, size_t ws_size,
                              hipStream_t stream) {
    const float* x      = (const float*)d_in[0];
    const float* ln_g   = (const float*)d_in[1];
    const float* ln_b   = (const float*)d_in[2];
    const float* w_up   = (const float*)d_in[3];
    const float* b_up   = (const float*)d_in[4];
    const float* w_q    = (const float*)d_in[5];
    const float* b_q    = (const float*)d_in[6];
    const float* w_k    = (const float*)d_in[7];
    const float* b_k    = (const float*)d_in[8];
    const float* w_v    = (const float*)d_in[9];
    const float* b_v    = (const float*)d_in[10];
    const float* w_conv = (const float*)d_in[11];
    const float* b_conv = (const float*)d_in[12];
    const float* w_ig   = (const float*)d_in[13];
    const float* b_ig   = (const float*)d_in[14];
    const float* w_fg   = (const float*)d_in[15];
    const float* b_fg   = (const float*)d_in[16];
    const float* on_g   = (const float*)d_in[17];
    const float* on_b   = (const float*)d_in[18];
    const float* skip   = (const float*)d_in[19];
    const float* w_down = (const float*)d_in[20];
    const float* b_down = (const float*)d_in[21];

    float* ws = (float*)d_ws;
    const size_t NSI = (size_t)NB * SEQ * INNER;       // 221184
    const size_t NHS = (size_t)NB * NHEAD * SEQ;       // 55296
    float* xm  = ws;                // x_mlstm   [B][S][192]
    float* z   = xm + NSI;          // z
    float* xc  = z + NSI;           // x_conv
    float* qw  = xc + NSI;          // q [B][NH][S][4]
    float* kw  = qw + NSI;
    float* vw  = kw + NSI;
    float* igw = vw + NSI;          // ig [B][NH][S]
    float* fgw = igw + NHS;
    float* m_g = fgw + NHS;         // m  [B][NH][S]
    float* M_g = m_g + NHS;         // prefix max
    float* lfc = M_g + NHS;         // lf_cum[t+1]
    float* ht  = lfc + NHS;         // h_tilde [B][NH][S][4]

    float* out = (float*)d_out;

    dim3 gBS(NB * SEQ);
    hipLaunchKernelGGL(k_ln_up, gBS, dim3(128), 0, stream, x, ln_g, ln_b, w_up, b_up, xm, z);
    hipLaunchKernelGGL(k_conv_qkv_gates, gBS, dim3(192), 0, stream, xm, w_conv, b_conv,
                       w_q, b_q, w_k, b_k, w_v, b_v, w_ig, b_ig, w_fg, b_fg,
                       xc, qw, kw, vw, igw, fgw);
    hipLaunchKernelGGL(k_scan, dim3(NB * NHEAD), dim3(64), 0, stream, igw, fgw, m_g, M_g, lfc);
    hipLaunchKernelGGL(k_mlstm, dim3(NB * NHEAD, SEQ / RT), dim3(256), 0, stream,
                       qw, kw, vw, m_g, M_g, lfc, ht);
    hipLaunchKernelGGL(k_epilogue, gBS, dim3(192), 0, stream, ht, on_g, on_b, skip,
                       xc, z, w_down, b_down, x, out);
}

// Round 3
// 94.967 us; speedup vs baseline: 1.9543x; 1.9543x over previous
//
#include <hip/hip_runtime.h>
#include <math.h>

#define SEQ   576     // H*W = 24*24
#define CDIM  96
#define INNER 192
#define NHEAD 48
#define DH    4
#define NB    2
#define EPSV  1e-5f
#define RT    64      // mlstm row-tile

__device__ __forceinline__ float silu_f(float x) { return x / (1.f + __expf(-x)); }
__device__ __forceinline__ float logsig_f(float x) {
    return (x >= 0.f) ? -log1pf(__expf(-x)) : (x - log1pf(__expf(x)));
}

// ---------------- Kernel A: LayerNorm + up-projection (96 -> 384) ----------------
__global__ void k_ln_up(const float* __restrict__ x, const float* __restrict__ ln_g,
                        const float* __restrict__ ln_b, const float* __restrict__ w_up,
                        const float* __restrict__ b_up,
                        float* __restrict__ xm, float* __restrict__ z) {
    const int bs = blockIdx.x;
    const int b = bs / SEQ, s = bs % SEQ;
    const int t = threadIdx.x;                 // 128 threads
    __shared__ float red[128];
    __shared__ float hbuf[CDIM];

    float val = 0.f;
    if (t < CDIM) val = x[(size_t)(b * CDIM + t) * SEQ + s];
    red[t] = val;
    __syncthreads();
    for (int off = 64; off > 0; off >>= 1) { if (t < off) red[t] += red[t + off]; __syncthreads(); }
    const float mean = red[0] * (1.f / CDIM);
    __syncthreads();
    float d = (t < CDIM) ? (val - mean) : 0.f;
    red[t] = d * d;
    __syncthreads();
    for (int off = 64; off > 0; off >>= 1) { if (t < off) red[t] += red[t + off]; __syncthreads(); }
    const float rstd = rsqrtf(red[0] * (1.f / CDIM) + EPSV);
    if (t < CDIM) hbuf[t] = (val - mean) * rstd * ln_g[t] + ln_b[t];
    __syncthreads();

    for (int f = t; f < 2 * INNER; f += 128) {
        float acc = b_up[f];
        const float* wr = w_up + (size_t)f * CDIM;
        #pragma unroll 8
        for (int c = 0; c < CDIM; ++c) acc += hbuf[c] * wr[c];
        if (f < INNER) xm[(size_t)(b * SEQ + s) * INNER + f] = acc;
        else           z [(size_t)(b * SEQ + s) * INNER + (f - INNER)] = acc;
    }
}

// ------------- Kernel B: causal conv + SiLU, headwise q/k/v (no gates) -------------
__global__ void k_conv_qkv(const float* __restrict__ xm,
    const float* __restrict__ w_conv, const float* __restrict__ b_conv,
    const float* __restrict__ w_q, const float* __restrict__ b_q,
    const float* __restrict__ w_k, const float* __restrict__ b_k,
    const float* __restrict__ w_v, const float* __restrict__ b_v,
    float* __restrict__ xc, float* __restrict__ qw, float* __restrict__ kw,
    float* __restrict__ vw, float* __restrict__ qkvp) {
    const int bs = blockIdx.x;
    const int b = bs / SEQ, s = bs % SEQ;
    const int t = threadIdx.x;   // 192 threads
    __shared__ float xc_l[INNER], xm_l[INNER];

    {
        float acc = b_conv[t];
        #pragma unroll
        for (int j = 0; j < 4; ++j) {
            int ss = s - 3 + j;
            if (ss >= 0) acc += xm[(size_t)(b * SEQ + ss) * INNER + t] * w_conv[t * 4 + j];
        }
        float v = silu_f(acc);
        xc_l[t] = v;
        xc[(size_t)(b * SEQ + s) * INNER + t] = v;
        xm_l[t] = xm[(size_t)(b * SEQ + s) * INNER + t];
    }
    __syncthreads();
    {
        const int n = t >> 2, o = t & 3;
        const float* wq = w_q + n * 16 + o * 4;
        const float* wk = w_k + n * 16 + o * 4;
        const float* wv = w_v + n * 16 + o * 4;
        float q = b_q[t], k = b_k[t], v = b_v[t];
        #pragma unroll
        for (int dd = 0; dd < 4; ++dd) {
            q += xc_l[n * 4 + dd] * wq[dd];
            k += xc_l[n * 4 + dd] * wk[dd];
            v += xm_l[n * 4 + dd] * wv[dd];
        }
        // head-major for k_mlstm
        size_t base = ((size_t)(b * NHEAD + n) * SEQ + s) * DH + o;
        qw[base] = q; kw[base] = k; vw[base] = v;
        // position-major for k_gates (coalesced: lane t -> feature t)
        size_t pb = (size_t)bs * (3 * INNER);
        qkvp[pb + t] = q; qkvp[pb + INNER + t] = k; qkvp[pb + 2 * INNER + t] = v;
    }
}

// ------------- Kernel B2: gate GEMM  C[1152][96] = qkv[1152][576] . W[96][576]^T -------
// 16 lanes per output, k-major lane axis -> coalesced float4 loads of both operands.
__global__ void __launch_bounds__(256) k_gates(const float* __restrict__ qkvp,
    const float* __restrict__ w_ig, const float* __restrict__ b_ig,
    const float* __restrict__ w_fg, const float* __restrict__ b_fg,
    float* __restrict__ igw, float* __restrict__ fgw) {
    const int t = threadIdx.x;
    const int lane = t & 15;                  // k-slice: 16 x 36 = 576
    const int oi = t >> 4;                    // 16 outputs per block
    const int og = oi & 3, op = oi >> 2;      // 4 gates x 4 positions
    const int pos = blockIdx.x * 4 + op;      // 0..1151
    const int g   = blockIdx.y * 4 + og;      // 0..95 (ig: 0..47, fg: 48..95)
    const int b = pos / SEQ, s = pos % SEQ;
    const bool isfg = (g >= NHEAD);
    const int h = isfg ? (g - NHEAD) : g;
    const float4* xr = (const float4*)(qkvp + (size_t)pos * (3 * INNER)) + lane * 9;
    const float4* wr = (const float4*)((isfg ? w_fg : w_ig) + (size_t)h * (3 * INNER)) + lane * 9;
    float acc = 0.f;
    #pragma unroll
    for (int j = 0; j < 9; ++j) {
        float4 a = xr[j], w = wr[j];
        acc += a.x * w.x + a.y * w.y + a.z * w.z + a.w * w.w;
    }
    #pragma unroll
    for (int off = 1; off < 16; off <<= 1) acc += __shfl_xor(acc, off);
    if (lane == 0) {
        acc += isfg ? b_fg[h] : b_ig[h];
        (isfg ? fgw : igw)[((size_t)b * NHEAD + h) * SEQ + s] = acc;
    }
}

// ------------- Kernel C0: per-head sequence scans (lf_cum, m, prefix-max M) -------------
__global__ void k_scan(const float* __restrict__ igw, const float* __restrict__ fgw,
                       float* __restrict__ m_g, float* __restrict__ M_g,
                       float* __restrict__ lfc_g) {
    const int bh = blockIdx.x;   // 96 blocks
    const int t = threadIdx.x;   // 64 threads (one wave)
    const int base = t * 9;
    float pre[9], mv[9], mx[9];
    float run = 0.f;
    #pragma unroll
    for (int j = 0; j < 9; ++j) {
        run += logsig_f(fgw[(size_t)bh * SEQ + base + j]);
        pre[j] = run;
    }
    float incl = run;
    #pragma unroll
    for (int off = 1; off < 64; off <<= 1) {
        float o = __shfl_up(incl, off);
        if (t >= off) incl += o;
    }
    const float excl = incl - run;
    float runm = -INFINITY;
    #pragma unroll
    for (int j = 0; j < 9; ++j) {
        float lfc = excl + pre[j];                    // lf_cum[t+1]
        lfc_g[(size_t)bh * SEQ + base + j] = lfc;
        float mt = igw[(size_t)bh * SEQ + base + j] - lfc;
        mv[j] = mt;
        runm = fmaxf(runm, mt);
        mx[j] = runm;
    }
    float sc = runm;
    #pragma unroll
    for (int off = 1; off < 64; off <<= 1) {
        float o = __shfl_up(sc, off);
        if (t >= off) sc = fmaxf(sc, o);
    }
    float exclm = __shfl_up(sc, 1);
    if (t == 0) exclm = -INFINITY;
    #pragma unroll
    for (int j = 0; j < 9; ++j) {
        m_g[(size_t)bh * SEQ + base + j] = mv[j];
        M_g[(size_t)bh * SEQ + base + j] = fmaxf(exclm, mx[j]);
    }
}

// ------------- Kernel C: mLSTM, tiled rows, 4 lanes per row -------------
__global__ void __launch_bounds__(256) k_mlstm(const float* __restrict__ qw,
    const float* __restrict__ kw, const float* __restrict__ vw,
    const float* __restrict__ m_g, const float* __restrict__ M_g,
    const float* __restrict__ lfc_g, float* __restrict__ ht) {
    const int bh = blockIdx.x;          // 96
    const int r0 = blockIdx.y * RT;     // 9 tiles of 64 rows
    const int nt = r0 + RT;             // columns needed: [0, nt)
    const int t = threadIdx.x;          // 256 threads = 64 rows x 4 lanes
    __shared__ float4 k4[SEQ], v4[SEQ];
    __shared__ float m_l[SEQ];

    const float4* kb = (const float4*)(kw + (size_t)bh * SEQ * DH);
    const float4* vb = (const float4*)(vw + (size_t)bh * SEQ * DH);
    for (int i = t; i < nt; i += 256) {
        k4[i] = kb[i]; v4[i] = vb[i];
        m_l[i] = m_g[(size_t)bh * SEQ + i];
    }
    __syncthreads();

    const int sub = t & 3;
    const int s0 = r0 + (t >> 2);
    const float4 q = ((const float4*)(qw + (size_t)bh * SEQ * DH))[s0];
    const float Ms = M_g[(size_t)bh * SEQ + s0];
    const float lfcs = lfc_g[(size_t)bh * SEQ + s0];

    float a0 = 0.f, a1 = 0.f, a2 = 0.f, a3 = 0.f, csum = 0.f;
    for (int tt = sub; tt <= s0; tt += 4) {
        float e = __expf(m_l[tt] - Ms);
        float4 kk = k4[tt], vv = v4[tt];
        float qk = q.x * kk.x + q.y * kk.y + q.z * kk.z + q.w * kk.w;
        float c = qk * 0.5f * e;                       // DH^-0.5 = 0.5
        csum += c;
        a0 += c * vv.x; a1 += c * vv.y; a2 += c * vv.z; a3 += c * vv.w;
    }
    #pragma unroll
    for (int off = 1; off < 4; off <<= 1) {
        csum += __shfl_xor(csum, off);
        a0 += __shfl_xor(a0, off); a1 += __shfl_xor(a1, off);
        a2 += __shfl_xor(a2, off); a3 += __shfl_xor(a3, off);
    }
    const float floorv = __expf(-(lfcs + Ms));
    const float inv = 1.f / (fmaxf(fabsf(csum), floorv) + 1e-6f);
    const float val = (sub == 0) ? a0 : (sub == 1) ? a1 : (sub == 2) ? a2 : a3;
    ht[((size_t)bh * SEQ + s0) * 4 + sub] = val * inv;
}

// ------------- Kernel D: per-head LN, skip, z-gate, down-proj, residual -------------
__global__ void k_epilogue(const float* __restrict__ ht, const float* __restrict__ on_g,
    const float* __restrict__ on_b, const float* __restrict__ skip,
    const float* __restrict__ xc, const float* __restrict__ z,
    const float* __restrict__ w_down, const float* __restrict__ b_down,
    const float* __restrict__ x, float* __restrict__ out) {
    const int bs = blockIdx.x;
    const int b = bs / SEQ, s = bs % SEQ;
    const int t = threadIdx.x;   // 192 threads
    __shared__ float ht_l[INNER], hs_l[INNER];
    const int n = t >> 2;

    ht_l[t] = ht[((size_t)(b * NHEAD + n) * SEQ + s) * DH + (t & 3)];
    __syncthreads();
    const float h0 = ht_l[n * 4], h1 = ht_l[n * 4 + 1], h2 = ht_l[n * 4 + 2], h3 = ht_l[n * 4 + 3];
    const float mean = (h0 + h1 + h2 + h3) * 0.25f;
    const float d0 = h0 - mean, d1 = h1 - mean, d2 = h2 - mean, d3 = h3 - mean;
    const float var = (d0 * d0 + d1 * d1 + d2 * d2 + d3 * d3) * 0.25f;
    const float rstd = rsqrtf(var + EPSV);
    const float hn = (ht_l[t] - mean) * rstd * on_g[t] + on_b[t];
    const float hskip = hn + skip[t] * xc[(size_t)(b * SEQ + s) * INNER + t];
    const float zv = z[(size_t)(b * SEQ + s) * INNER + t];
    hs_l[t] = hskip * silu_f(zv);
    __syncthreads();

    if (t < CDIM) {
        float acc = b_down[t];
        const float* wr = w_down + (size_t)t * INNER;
        #pragma unroll 8
        for (int d = 0; d < INNER; ++d) acc += hs_l[d] * wr[d];
        size_t idx = ((size_t)b * CDIM + t) * SEQ + s;
        out[idx] = x[idx] + acc;
    }
}

extern "C" void kernel_launch(void* const* d_in, const int* in_sizes, int n_in,
                              void* d_out, int out_size, void* d_ws, size_t ws_size,
                              hipStream_t stream) {
    const float* x      = (const float*)d_in[0];
    const float* ln_g   = (const float*)d_in[1];
    const float* ln_b   = (const float*)d_in[2];
    const float* w_up   = (const float*)d_in[3];
    const float* b_up   = (const float*)d_in[4];
    const float* w_q    = (const float*)d_in[5];
    const float* b_q    = (const float*)d_in[6];
    const float* w_k    = (const float*)d_in[7];
    const float* b_k    = (const float*)d_in[8];
    const float* w_v    = (const float*)d_in[9];
    const float* b_v    = (const float*)d_in[10];
    const float* w_conv = (const float*)d_in[11];
    const float* b_conv = (const float*)d_in[12];
    const float* w_ig   = (const float*)d_in[13];
    const float* b_ig   = (const float*)d_in[14];
    const float* w_fg   = (const float*)d_in[15];
    const float* b_fg   = (const float*)d_in[16];
    const float* on_g   = (const float*)d_in[17];
    const float* on_b   = (const float*)d_in[18];
    const float* skip   = (const float*)d_in[19];
    const float* w_down = (const float*)d_in[20];
    const float* b_down = (const float*)d_in[21];

    float* ws = (float*)d_ws;
    const size_t NSI = (size_t)NB * SEQ * INNER;       // 221184
    const size_t NHS = (size_t)NB * NHEAD * SEQ;       // 55296
    float* xm   = ws;               // x_mlstm   [B][S][192]
    float* z    = xm + NSI;         // z
    float* xc   = z + NSI;          // x_conv
    float* qw   = xc + NSI;         // q [B][NH][S][4]
    float* kw   = qw + NSI;
    float* vw   = kw + NSI;
    float* qkvp = vw + NSI;         // qkv position-major [B*S][576]
    float* igw  = qkvp + 3 * NSI;   // ig [B][NH][S]
    float* fgw  = igw + NHS;
    float* m_g  = fgw + NHS;
    float* M_g  = m_g + NHS;
    float* lfc  = M_g + NHS;
    float* ht   = lfc + NHS;        // h_tilde [B][NH][S][4]

    float* out = (float*)d_out;

    dim3 gBS(NB * SEQ);
    hipLaunchKernelGGL(k_ln_up, gBS, dim3(128), 0, stream, x, ln_g, ln_b, w_up, b_up, xm, z);
    hipLaunchKernelGGL(k_conv_qkv, gBS, dim3(192), 0, stream, xm, w_conv, b_conv,
                       w_q, b_q, w_k, b_k, w_v, b_v, xc, qw, kw, vw, qkvp);
    hipLaunchKernelGGL(k_gates, dim3(NB * SEQ / 4, 96 / 4), dim3(256), 0, stream,
                       qkvp, w_ig, b_ig, w_fg, b_fg, igw, fgw);
    hipLaunchKernelGGL(k_scan, dim3(NB * NHEAD), dim3(64), 0, stream, igw, fgw, m_g, M_g, lfc);
    hipLaunchKernelGGL(k_mlstm, dim3(NB * NHEAD, SEQ / RT), dim3(256), 0, stream,
                       qw, kw, vw, m_g, M_g, lfc, ht);
    hipLaunchKernelGGL(k_epilogue, gBS, dim3(192), 0, stream, ht, on_g, on_b, skip,
                       xc, z, w_down, b_down, x, out);
}

// Round 4
// 83.858 us; speedup vs baseline: 2.2132x; 1.1325x over previous
//
#include <hip/hip_runtime.h>
#include <math.h>

#define SEQ   576     // H*W = 24*24
#define CDIM  96
#define INNER 192
#define NHEAD 48
#define DH    4
#define NB    2
#define EPSV  1e-5f
#define RT    64      // mlstm row-tile

__device__ __forceinline__ float silu_f(float x) { return x / (1.f + __expf(-x)); }
__device__ __forceinline__ float logsig_f(float x) {
    return (x >= 0.f) ? -log1pf(__expf(-x)) : (x - log1pf(__expf(x)));
}

// ---------------- K1: LayerNorm with LDS tile-transpose (16 positions/block) ----------------
__global__ void __launch_bounds__(256) k_ln(const float* __restrict__ x,
    const float* __restrict__ ln_g, const float* __restrict__ ln_b,
    float* __restrict__ h) {
    const int blk = blockIdx.x;               // NB*36 = 72
    const int b = blk / 36, s0 = (blk % 36) * 16;
    const int t = threadIdx.x;                // 256
    __shared__ float xt[16][CDIM + 1];
    __shared__ float mu[16], rs[16];

    // coalesced load: 96 channels x 4 float4 (16 positions each)
    for (int i = t; i < 384; i += 256) {
        const int c = i >> 2, j = i & 3;
        const float4 v = ((const float4*)x)[(size_t)(b * CDIM + c) * (SEQ / 4) + (s0 >> 2) + j];
        xt[j * 4 + 0][c] = v.x; xt[j * 4 + 1][c] = v.y;
        xt[j * 4 + 2][c] = v.z; xt[j * 4 + 3][c] = v.w;
    }
    __syncthreads();
    {
        const int g = t >> 4, l = t & 15;     // 16 positions x 16 lanes
        float sum = 0.f;
        #pragma unroll
        for (int k = 0; k < 6; ++k) sum += xt[g][l + 16 * k];
        #pragma unroll
        for (int off = 1; off < 16; off <<= 1) sum += __shfl_xor(sum, off);
        const float mean = sum * (1.f / CDIM);
        float vs = 0.f;
        #pragma unroll
        for (int k = 0; k < 6; ++k) { float d = xt[g][l + 16 * k] - mean; vs += d * d; }
        #pragma unroll
        for (int off = 1; off < 16; off <<= 1) vs += __shfl_xor(vs, off);
        if (l == 0) { mu[g] = mean; rs[g] = rsqrtf(vs * (1.f / CDIM) + EPSV); }
    }
    __syncthreads();
    for (int i = t; i < 16 * CDIM; i += 256) {
        const int p = i / CDIM, c = i % CDIM;
        h[(size_t)(b * SEQ + s0 + p) * CDIM + c] = (xt[p][c] - mu[p]) * rs[p] * ln_g[c] + ln_b[c];
    }
}

// ---------------- K2: up-proj GEMM  [1152x96] . [384x96]^T  (8 lanes/output) ----------------
__global__ void __launch_bounds__(256) k_up(const float* __restrict__ h,
    const float* __restrict__ w_up, const float* __restrict__ b_up,
    float* __restrict__ xm, float* __restrict__ z) {
    const int t = threadIdx.x;
    const int lane = t & 7, oi = t >> 3;       // 32 outputs: 4 pos x 8 feat
    const int op = oi & 3, of = oi >> 2;
    const int pos = blockIdx.x * 4 + op;       // 0..1151
    const int f   = blockIdx.y * 8 + of;       // 0..383
    const float4* hr = (const float4*)(h + (size_t)pos * CDIM) + lane * 3;
    const float4* wr = (const float4*)(w_up + (size_t)f * CDIM) + lane * 3;
    float acc = 0.f;
    #pragma unroll
    for (int j = 0; j < 3; ++j) {
        float4 a = hr[j], w = wr[j];
        acc += a.x * w.x + a.y * w.y + a.z * w.z + a.w * w.w;
    }
    #pragma unroll
    for (int off = 1; off < 8; off <<= 1) acc += __shfl_xor(acc, off);
    if (lane == 0) {
        acc += b_up[f];
        if (f < INNER) xm[(size_t)pos * INNER + f] = acc;
        else           z [(size_t)pos * INNER + (f - INNER)] = acc;
    }
}

// ------------- K3: causal conv + SiLU, headwise q/k/v -------------
__global__ void k_conv_qkv(const float* __restrict__ xm,
    const float* __restrict__ w_conv, const float* __restrict__ b_conv,
    const float* __restrict__ w_q, const float* __restrict__ b_q,
    const float* __restrict__ w_k, const float* __restrict__ b_k,
    const float* __restrict__ w_v, const float* __restrict__ b_v,
    float* __restrict__ xc, float* __restrict__ qw, float* __restrict__ kw,
    float* __restrict__ vw, float* __restrict__ qkvp) {
    const int bs = blockIdx.x;
    const int b = bs / SEQ, s = bs % SEQ;
    const int t = threadIdx.x;   // 192 threads
    __shared__ float xc_l[INNER], xm_l[INNER];

    {
        float acc = b_conv[t];
        #pragma unroll
        for (int j = 0; j < 4; ++j) {
            int ss = s - 3 + j;
            if (ss >= 0) acc += xm[(size_t)(b * SEQ + ss) * INNER + t] * w_conv[t * 4 + j];
        }
        float v = silu_f(acc);
        xc_l[t] = v;
        xc[(size_t)(b * SEQ + s) * INNER + t] = v;
        xm_l[t] = xm[(size_t)(b * SEQ + s) * INNER + t];
    }
    __syncthreads();
    {
        const int n = t >> 2, o = t & 3;
        const float* wq = w_q + n * 16 + o * 4;
        const float* wk = w_k + n * 16 + o * 4;
        const float* wv = w_v + n * 16 + o * 4;
        float q = b_q[t], k = b_k[t], v = b_v[t];
        #pragma unroll
        for (int dd = 0; dd < 4; ++dd) {
            q += xc_l[n * 4 + dd] * wq[dd];
            k += xc_l[n * 4 + dd] * wk[dd];
            v += xm_l[n * 4 + dd] * wv[dd];
        }
        size_t base = ((size_t)(b * NHEAD + n) * SEQ + s) * DH + o;
        qw[base] = q; kw[base] = k; vw[base] = v;
        size_t pb = (size_t)bs * (3 * INNER);
        qkvp[pb + t] = q; qkvp[pb + INNER + t] = k; qkvp[pb + 2 * INNER + t] = v;
    }
}

// ------------- K4: gate GEMM  [1152][96] = qkv[1152][576] . W[96][576]^T -------
__global__ void __launch_bounds__(256) k_gates(const float* __restrict__ qkvp,
    const float* __restrict__ w_ig, const float* __restrict__ b_ig,
    const float* __restrict__ w_fg, const float* __restrict__ b_fg,
    float* __restrict__ igw, float* __restrict__ fgw) {
    const int t = threadIdx.x;
    const int lane = t & 15;                  // k-slice: 16 x 36 = 576
    const int oi = t >> 4;                    // 16 outputs per block
    const int og = oi & 3, op = oi >> 2;      // 4 gates x 4 positions
    const int pos = blockIdx.x * 4 + op;      // 0..1151
    const int g   = blockIdx.y * 4 + og;      // 0..95
    const int b = pos / SEQ, s = pos % SEQ;
    const bool isfg = (g >= NHEAD);
    const int h = isfg ? (g - NHEAD) : g;
    const float4* xr = (const float4*)(qkvp + (size_t)pos * (3 * INNER)) + lane * 9;
    const float4* wr = (const float4*)((isfg ? w_fg : w_ig) + (size_t)h * (3 * INNER)) + lane * 9;
    float acc = 0.f;
    #pragma unroll
    for (int j = 0; j < 9; ++j) {
        float4 a = xr[j], w = wr[j];
        acc += a.x * w.x + a.y * w.y + a.z * w.z + a.w * w.w;
    }
    #pragma unroll
    for (int off = 1; off < 16; off <<= 1) acc += __shfl_xor(acc, off);
    if (lane == 0) {
        acc += isfg ? b_fg[h] : b_ig[h];
        (isfg ? fgw : igw)[((size_t)b * NHEAD + h) * SEQ + s] = acc;
    }
}

// ------------- K5: mLSTM with fused per-block scan, tiled rows, 4 lanes/row -------------
// Dm[s,t] = exp(m[t] - M[s]); max_log_D[s] = lf_cum[s+1] + M[s]
__global__ void __launch_bounds__(256) k_mlstm(const float* __restrict__ qw,
    const float* __restrict__ kw, const float* __restrict__ vw,
    const float* __restrict__ igw, const float* __restrict__ fgw,
    float* __restrict__ ht) {
    const int bh = blockIdx.x;          // 96
    const int r0 = blockIdx.y * RT;     // 9 tiles of 64 rows
    const int nt = r0 + RT;
    const int t = threadIdx.x;          // 256
    __shared__ float4 k4[SEQ], v4[SEQ];
    __shared__ float m_l[SEQ], M_l[SEQ], lfc_l[SEQ];

    const float4* kb = (const float4*)(kw + (size_t)bh * SEQ * DH);
    const float4* vb = (const float4*)(vw + (size_t)bh * SEQ * DH);
    for (int i = t; i < nt; i += 256) { k4[i] = kb[i]; v4[i] = vb[i]; }

    if (t < 64) {                // wave-0 scans: 64 lanes x 9 elems = 576
        const int base = t * 9;
        float pre[9], mv[9], mx[9];
        float run = 0.f;
        #pragma unroll
        for (int j = 0; j < 9; ++j) {
            run += logsig_f(fgw[(size_t)bh * SEQ + base + j]);
            pre[j] = run;
        }
        float incl = run;
        #pragma unroll
        for (int off = 1; off < 64; off <<= 1) {
            float o = __shfl_up(incl, off);
            if (t >= off) incl += o;
        }
        const float excl = incl - run;
        float runm = -INFINITY;
        #pragma unroll
        for (int j = 0; j < 9; ++j) {
            float lfc = excl + pre[j];                  // lf_cum[t+1]
            lfc_l[base + j] = lfc;
            float mt = igw[(size_t)bh * SEQ + base + j] - lfc;
            mv[j] = mt;
            runm = fmaxf(runm, mt);
            mx[j] = runm;
        }
        float sc = runm;
        #pragma unroll
        for (int off = 1; off < 64; off <<= 1) {
            float o = __shfl_up(sc, off);
            if (t >= off) sc = fmaxf(sc, o);
        }
        float exclm = __shfl_up(sc, 1);
        if (t == 0) exclm = -INFINITY;
        #pragma unroll
        for (int j = 0; j < 9; ++j) {
            m_l[base + j] = mv[j];
            M_l[base + j] = fmaxf(exclm, mx[j]);
        }
    }
    __syncthreads();

    const int sub = t & 3;
    const int s0 = r0 + (t >> 2);
    const float4 q = ((const float4*)(qw + (size_t)bh * SEQ * DH))[s0];
    const float Ms = M_l[s0], lfcs = lfc_l[s0];

    float a0 = 0.f, a1 = 0.f, a2 = 0.f, a3 = 0.f, csum = 0.f;
    for (int tt = sub; tt <= s0; tt += 4) {
        float e = __expf(m_l[tt] - Ms);
        float4 kk = k4[tt], vv = v4[tt];
        float qk = q.x * kk.x + q.y * kk.y + q.z * kk.z + q.w * kk.w;
        float c = qk * 0.5f * e;                       // DH^-0.5 = 0.5
        csum += c;
        a0 += c * vv.x; a1 += c * vv.y; a2 += c * vv.z; a3 += c * vv.w;
    }
    #pragma unroll
    for (int off = 1; off < 4; off <<= 1) {
        csum += __shfl_xor(csum, off);
        a0 += __shfl_xor(a0, off); a1 += __shfl_xor(a1, off);
        a2 += __shfl_xor(a2, off); a3 += __shfl_xor(a3, off);
    }
    const float floorv = __expf(-(lfcs + Ms));
    const float inv = 1.f / (fmaxf(fabsf(csum), floorv) + 1e-6f);
    const float val = (sub == 0) ? a0 : (sub == 1) ? a1 : (sub == 2) ? a2 : a3;
    ht[((size_t)bh * SEQ + s0) * 4 + sub] = val * inv;
}

// ------------- K6: fused epilogue: per-head LN + skip + z-gate (phase 1, LDS),
//                   then down-GEMM + residual + transposed store (phase 2) -------------
__global__ void __launch_bounds__(256) k_epi(const float* __restrict__ ht,
    const float* __restrict__ on_g, const float* __restrict__ on_b,
    const float* __restrict__ skip, const float* __restrict__ xc,
    const float* __restrict__ zz, const float* __restrict__ w_down,
    const float* __restrict__ b_down, const float* __restrict__ x,
    float* __restrict__ out) {
    const int t = threadIdx.x;
    const int p0 = blockIdx.x * 4;             // 4 positions per block
    const int b = p0 / SEQ;                    // same b for all 4 (576 % 4 == 0)
    __shared__ float hs[4][INNER];

    // phase 1: hs[p][c] = (mhLN(ht) + skip*xc) * silu(z)
    for (int i = t; i < 4 * INNER; i += 256) {
        const int p = i / INNER, c = i % INNER;
        const int pos = p0 + p, s = pos % SEQ;
        const int n = c >> 2, o = c & 3;
        const float4 hv = ((const float4*)ht)[(size_t)(b * NHEAD + n) * SEQ + s];
        const float mean = (hv.x + hv.y + hv.z + hv.w) * 0.25f;
        const float d0 = hv.x - mean, d1 = hv.y - mean, d2 = hv.z - mean, d3 = hv.w - mean;
        const float var = (d0 * d0 + d1 * d1 + d2 * d2 + d3 * d3) * 0.25f;
        const float rstd = rsqrtf(var + EPSV);
        const float he = (o == 0) ? hv.x : (o == 1) ? hv.y : (o == 2) ? hv.z : hv.w;
        const float hn = (he - mean) * rstd * on_g[c] + on_b[c];
        const float hk = hn + skip[c] * xc[(size_t)pos * INNER + c];
        hs[p][c] = hk * silu_f(zz[(size_t)pos * INNER + c]);
    }
    __syncthreads();

    // phase 2: out[b][c][s] = x + hs . w_down[c] + b_down[c]
    const int lane = t & 7, oi = t >> 3;       // 32 outputs: 4 pos x 8 channels
    const int op = oi & 3, oc = oi >> 2;
    const int c = blockIdx.y * 8 + oc;         // 0..95
    const int pos = p0 + op, s = pos % SEQ;
    const float4* hr = (const float4*)(&hs[op][0]) + lane * 6;
    const float4* wr = (const float4*)(w_down + (size_t)c * INNER) + lane * 6;
    float acc = 0.f;
    #pragma unroll
    for (int j = 0; j < 6; ++j) {
        float4 a = hr[j], w = wr[j];
        acc += a.x * w.x + a.y * w.y + a.z * w.z + a.w * w.w;
    }
    #pragma unroll
    for (int off = 1; off < 8; off <<= 1) acc += __shfl_xor(acc, off);
    if (lane == 0) {
        const size_t idx = ((size_t)b * CDIM + c) * SEQ + s;
        out[idx] = x[idx] + acc + b_down[c];
    }
}

extern "C" void kernel_launch(void* const* d_in, const int* in_sizes, int n_in,
                              void* d_out, int out_size, void* d_ws, size_t ws_size,
                              hipStream_t stream) {
    const float* x      = (const float*)d_in[0];
    const float* ln_g   = (const float*)d_in[1];
    const float* ln_b   = (const float*)d_in[2];
    const float* w_up   = (const float*)d_in[3];
    const float* b_up   = (const float*)d_in[4];
    const float* w_q    = (const float*)d_in[5];
    const float* b_q    = (const float*)d_in[6];
    const float* w_k    = (const float*)d_in[7];
    const float* b_k    = (const float*)d_in[8];
    const float* w_v    = (const float*)d_in[9];
    const float* b_v    = (const float*)d_in[10];
    const float* w_conv = (const float*)d_in[11];
    const float* b_conv = (const float*)d_in[12];
    const float* w_ig   = (const float*)d_in[13];
    const float* b_ig   = (const float*)d_in[14];
    const float* w_fg   = (const float*)d_in[15];
    const float* b_fg   = (const float*)d_in[16];
    const float* on_g   = (const float*)d_in[17];
    const float* on_b   = (const float*)d_in[18];
    const float* skip   = (const float*)d_in[19];
    const float* w_down = (const float*)d_in[20];
    const float* b_down = (const float*)d_in[21];

    float* ws = (float*)d_ws;
    const size_t NSI = (size_t)NB * SEQ * INNER;       // 221184
    const size_t NHS = (size_t)NB * NHEAD * SEQ;       // 55296
    float* h    = ws;               // LN output [B*S][96]
    float* xm   = h + (size_t)NB * SEQ * CDIM;  // [B*S][192]
    float* z    = xm + NSI;
    float* xc   = z + NSI;
    float* qw   = xc + NSI;         // head-major [B][NH][S][4]
    float* kw   = qw + NSI;
    float* vw   = kw + NSI;
    float* qkvp = vw + NSI;         // position-major [B*S][576]
    float* igw  = qkvp + 3 * NSI;   // [B][NH][S]
    float* fgw  = igw + NHS;
    float* ht   = fgw + NHS;        // [B][NH][S][4]

    float* out = (float*)d_out;

    hipLaunchKernelGGL(k_ln, dim3(NB * 36), dim3(256), 0, stream, x, ln_g, ln_b, h);
    hipLaunchKernelGGL(k_up, dim3(NB * SEQ / 4, 48), dim3(256), 0, stream, h, w_up, b_up, xm, z);
    hipLaunchKernelGGL(k_conv_qkv, dim3(NB * SEQ), dim3(192), 0, stream, xm, w_conv, b_conv,
                       w_q, b_q, w_k, b_k, w_v, b_v, xc, qw, kw, vw, qkvp);
    hipLaunchKernelGGL(k_gates, dim3(NB * SEQ / 4, 24), dim3(256), 0, stream,
                       qkvp, w_ig, b_ig, w_fg, b_fg, igw, fgw);
    hipLaunchKernelGGL(k_mlstm, dim3(NB * NHEAD, SEQ / RT), dim3(256), 0, stream,
                       qw, kw, vw, igw, fgw, ht);
    hipLaunchKernelGGL(k_epi, dim3(NB * SEQ / 4, CDIM / 8), dim3(256), 0, stream,
                       ht, on_g, on_b, skip, xc, z, w_down, b_down, x, out);
}

// Round 5
// 60.307 us; speedup vs baseline: 3.0775x; 1.3905x over previous
//
#include <hip/hip_runtime.h>
#include <math.h>

#define SEQ   576     // H*W = 24*24
#define CDIM  96
#define INNER 192
#define NHEAD 48
#define DH    4
#define NB    2
#define EPSV  1e-5f
#define RT    64      // mlstm row-tile

__device__ __forceinline__ float silu_f(float x) { return x / (1.f + __expf(-x)); }
__device__ __forceinline__ float logsig_f(float x) {
    return (x >= 0.f) ? -log1pf(__expf(-x)) : (x - log1pf(__expf(x)));
}

// ---------------- K1: fused LayerNorm + up-proj GEMM ----------------
// grid (144, 2) x 512: 8 positions/block, y-slice of 192 output features.
__global__ void __launch_bounds__(512) k_ln_up(const float* __restrict__ x,
    const float* __restrict__ ln_g, const float* __restrict__ ln_b,
    const float* __restrict__ w_up, const float* __restrict__ b_up,
    float* __restrict__ xm, float* __restrict__ z) {
    const int t = threadIdx.x;
    const int p0 = blockIdx.x * 8;             // 8 positions, same batch (576%8==0)
    const int b = p0 / SEQ;
    const int f0 = blockIdx.y * 192;
    __shared__ __align__(16) float hbuf[8][CDIM];

    // phase 1: LN for 8 positions (64 lanes each)
    {
        const int p = t >> 6, l = t & 63;
        const int s = (p0 + p) % SEQ;
        const float v0 = x[(size_t)(b * CDIM + l) * SEQ + s];
        const float v1 = (l < 32) ? x[(size_t)(b * CDIM + 64 + l) * SEQ + s] : 0.f;
        float sum = v0 + v1, sq = v0 * v0 + v1 * v1;
        #pragma unroll
        for (int off = 1; off < 64; off <<= 1) {
            sum += __shfl_xor(sum, off);
            sq  += __shfl_xor(sq, off);
        }
        const float mean = sum * (1.f / CDIM);
        const float var = sq * (1.f / CDIM) - mean * mean;
        const float rstd = rsqrtf(var + EPSV);
        hbuf[p][l] = (v0 - mean) * rstd * ln_g[l] + ln_b[l];
        if (l < 32) hbuf[p][64 + l] = (v1 - mean) * rstd * ln_g[64 + l] + ln_b[64 + l];
    }
    __syncthreads();

    // phase 2: 8 pos x 192 feats, 8 lanes per output, 24 sequential feats/thread
    const int lane = t & 7, oi = t >> 3;       // oi in [0,64)
    const int p2 = oi & 7, fg = oi >> 3;       // 8 pos x 8 feat-groups
    const int pos = p0 + p2;
    const float4* hr = (const float4*)(&hbuf[p2][0]) + lane * 3;
    const float4 h0 = hr[0], h1 = hr[1], h2 = hr[2];
    #pragma unroll 4
    for (int j = 0; j < 24; ++j) {
        const int f = f0 + fg + 8 * j;
        const float4* wr = (const float4*)(w_up + (size_t)f * CDIM) + lane * 3;
        float4 w0 = wr[0], w1 = wr[1], w2 = wr[2];
        float acc = h0.x * w0.x + h0.y * w0.y + h0.z * w0.z + h0.w * w0.w
                  + h1.x * w1.x + h1.y * w1.y + h1.z * w1.z + h1.w * w1.w
                  + h2.x * w2.x + h2.y * w2.y + h2.z * w2.z + h2.w * w2.w;
        #pragma unroll
        for (int off = 1; off < 8; off <<= 1) acc += __shfl_xor(acc, off);
        if (lane == 0) {
            acc += b_up[f];
            if (f < INNER) xm[(size_t)pos * INNER + f] = acc;
            else           z [(size_t)pos * INNER + (f - INNER)] = acc;
        }
    }
}

// ------------- K2: causal conv + SiLU + headwise q/k/v + gate GEMM -------------
// grid (288) x 512: 4 positions/block.
__global__ void __launch_bounds__(512) k_conv_qkv_gates(const float* __restrict__ xm,
    const float* __restrict__ w_conv, const float* __restrict__ b_conv,
    const float* __restrict__ w_q, const float* __restrict__ b_q,
    const float* __restrict__ w_k, const float* __restrict__ b_k,
    const float* __restrict__ w_v, const float* __restrict__ b_v,
    const float* __restrict__ w_ig, const float* __restrict__ b_ig,
    const float* __restrict__ w_fg, const float* __restrict__ b_fg,
    float* __restrict__ xc, float* __restrict__ qw, float* __restrict__ kw,
    float* __restrict__ vw, float* __restrict__ igw, float* __restrict__ fgw) {
    const int t = threadIdx.x;
    const int p0 = blockIdx.x * 4;
    const int b = p0 / SEQ, s0 = p0 % SEQ;
    __shared__ float xmb[7][INNER];            // xm rows s0-3 .. s0+3
    __shared__ float xcb[4][INNER];
    __shared__ __align__(16) float qkvb[4][3 * INNER];

    for (int i = t; i < 7 * INNER; i += 512) {
        const int r = i / INNER, c = i % INNER;
        const int ss = s0 - 3 + r;
        xmb[r][c] = (ss >= 0) ? xm[(size_t)(b * SEQ + ss) * INNER + c] : 0.f;
    }
    __syncthreads();

    // conv + silu
    for (int i = t; i < 4 * INNER; i += 512) {
        const int p = i / INNER, c = i % INNER;
        float acc = b_conv[c];
        #pragma unroll
        for (int j = 0; j < 4; ++j) acc += xmb[p + j][c] * w_conv[c * 4 + j];
        const float v = silu_f(acc);
        xcb[p][c] = v;
        xc[(size_t)(b * SEQ + s0 + p) * INNER + c] = v;
    }
    __syncthreads();

    // headwise q/k/v
    for (int i = t; i < 4 * INNER; i += 512) {
        const int p = i / INNER, c = i % INNER;
        const int n = c >> 2, o = c & 3;
        const float* wq = w_q + n * 16 + o * 4;
        const float* wk = w_k + n * 16 + o * 4;
        const float* wv = w_v + n * 16 + o * 4;
        float q = b_q[c], k = b_k[c], v = b_v[c];
        #pragma unroll
        for (int dd = 0; dd < 4; ++dd) {
            q += xcb[p][n * 4 + dd] * wq[dd];
            k += xcb[p][n * 4 + dd] * wk[dd];
            v += xmb[p + 3][n * 4 + dd] * wv[dd];
        }
        qkvb[p][c] = q; qkvb[p][INNER + c] = k; qkvb[p][2 * INNER + c] = v;
        const size_t base = ((size_t)(b * NHEAD + n) * SEQ + s0 + p) * DH + o;
        qw[base] = q; kw[base] = k; vw[base] = v;
    }
    __syncthreads();

    // gates: 8 waves x 12 gates; 16 lanes/gate, weight row in regs reused x4 positions
    {
        const int w = t >> 6;                  // wave 0..7
        const int l16 = t & 15, gg = (t >> 4) & 3;
        #pragma unroll
        for (int it = 0; it < 3; ++it) {
            const int g = w * 12 + it * 4 + gg;            // 0..95
            const bool isfg = (g >= NHEAD);
            const int hh = isfg ? (g - NHEAD) : g;
            const float4* wr = (const float4*)((isfg ? w_fg : w_ig) + (size_t)hh * (3 * INNER)) + l16 * 9;
            float4 wf[9];
            #pragma unroll
            for (int j = 0; j < 9; ++j) wf[j] = wr[j];
            #pragma unroll
            for (int p = 0; p < 4; ++p) {
                const float4* xr = (const float4*)(&qkvb[p][0]) + l16 * 9;
                float acc = 0.f;
                #pragma unroll
                for (int j = 0; j < 9; ++j) {
                    const float4 a = xr[j];
                    acc += a.x * wf[j].x + a.y * wf[j].y + a.z * wf[j].z + a.w * wf[j].w;
                }
                #pragma unroll
                for (int off = 1; off < 16; off <<= 1) acc += __shfl_xor(acc, off);
                if (l16 == 0) {
                    acc += isfg ? b_fg[hh] : b_ig[hh];
                    (isfg ? fgw : igw)[((size_t)b * NHEAD + hh) * SEQ + s0 + p] = acc;
                }
            }
        }
    }
}

// ------------- K3: mLSTM with fused per-block scan, tiled rows, 4 lanes/row -------------
// Dm[s,t] = exp(m[t] - M[s]); max_log_D[s] = lf_cum[s+1] + M[s]
__global__ void __launch_bounds__(256) k_mlstm(const float* __restrict__ qw,
    const float* __restrict__ kw, const float* __restrict__ vw,
    const float* __restrict__ igw, const float* __restrict__ fgw,
    float* __restrict__ ht) {
    const int bh = blockIdx.x;          // 96
    const int r0 = blockIdx.y * RT;     // 9 tiles of 64 rows
    const int nt = r0 + RT;
    const int t = threadIdx.x;          // 256
    __shared__ float4 k4[SEQ], v4[SEQ];
    __shared__ float m_l[SEQ], M_l[SEQ], lfc_l[SEQ];

    const float4* kb = (const float4*)(kw + (size_t)bh * SEQ * DH);
    const float4* vb = (const float4*)(vw + (size_t)bh * SEQ * DH);
    for (int i = t; i < nt; i += 256) { k4[i] = kb[i]; v4[i] = vb[i]; }

    if (t < 64) {                // wave-0 scans: 64 lanes x 9 elems = 576
        const int base = t * 9;
        float pre[9], mv[9], mx[9];
        float run = 0.f;
        #pragma unroll
        for (int j = 0; j < 9; ++j) {
            run += logsig_f(fgw[(size_t)bh * SEQ + base + j]);
            pre[j] = run;
        }
        float incl = run;
        #pragma unroll
        for (int off = 1; off < 64; off <<= 1) {
            float o = __shfl_up(incl, off);
            if (t >= off) incl += o;
        }
        const float excl = incl - run;
        float runm = -INFINITY;
        #pragma unroll
        for (int j = 0; j < 9; ++j) {
            float lfc = excl + pre[j];                  // lf_cum[t+1]
            lfc_l[base + j] = lfc;
            float mt = igw[(size_t)bh * SEQ + base + j] - lfc;
            mv[j] = mt;
            runm = fmaxf(runm, mt);
            mx[j] = runm;
        }
        float sc = runm;
        #pragma unroll
        for (int off = 1; off < 64; off <<= 1) {
            float o = __shfl_up(sc, off);
            if (t >= off) sc = fmaxf(sc, o);
        }
        float exclm = __shfl_up(sc, 1);
        if (t == 0) exclm = -INFINITY;
        #pragma unroll
        for (int j = 0; j < 9; ++j) {
            m_l[base + j] = mv[j];
            M_l[base + j] = fmaxf(exclm, mx[j]);
        }
    }
    __syncthreads();

    const int sub = t & 3;
    const int s0 = r0 + (t >> 2);
    const float4 q = ((const float4*)(qw + (size_t)bh * SEQ * DH))[s0];
    const float Ms = M_l[s0], lfcs = lfc_l[s0];

    float a0 = 0.f, a1 = 0.f, a2 = 0.f, a3 = 0.f, csum = 0.f;
    for (int tt = sub; tt <= s0; tt += 4) {
        float e = __expf(m_l[tt] - Ms);
        float4 kk = k4[tt], vv = v4[tt];
        float qk = q.x * kk.x + q.y * kk.y + q.z * kk.z + q.w * kk.w;
        float c = qk * 0.5f * e;                       // DH^-0.5 = 0.5
        csum += c;
        a0 += c * vv.x; a1 += c * vv.y; a2 += c * vv.z; a3 += c * vv.w;
    }
    #pragma unroll
    for (int off = 1; off < 4; off <<= 1) {
        csum += __shfl_xor(csum, off);
        a0 += __shfl_xor(a0, off); a1 += __shfl_xor(a1, off);
        a2 += __shfl_xor(a2, off); a3 += __shfl_xor(a3, off);
    }
    const float floorv = __expf(-(lfcs + Ms));
    const float inv = 1.f / (fmaxf(fabsf(csum), floorv) + 1e-6f);
    const float val = (sub == 0) ? a0 : (sub == 1) ? a1 : (sub == 2) ? a2 : a3;
    ht[((size_t)bh * SEQ + s0) * 4 + sub] = val * inv;
}

// ------------- K4: epilogue: mhLN + skip + z-gate (phase 1), down-GEMM + residual (phase 2) ----
// grid (288) x 512: 4 positions/block, 6 sequential channels/thread in phase 2.
__global__ void __launch_bounds__(512) k_epi(const float* __restrict__ ht,
    const float* __restrict__ on_g, const float* __restrict__ on_b,
    const float* __restrict__ skip, const float* __restrict__ xc,
    const float* __restrict__ zz, const float* __restrict__ w_down,
    const float* __restrict__ b_down, const float* __restrict__ x,
    float* __restrict__ out) {
    const int t = threadIdx.x;
    const int p0 = blockIdx.x * 4;
    const int b = p0 / SEQ;
    __shared__ __align__(16) float hs[4][INNER];

    for (int i = t; i < 4 * INNER; i += 512) {
        const int p = i / INNER, c = i % INNER;
        const int pos = p0 + p, s = pos % SEQ;
        const int n = c >> 2, o = c & 3;
        const float4 hv = ((const float4*)ht)[(size_t)(b * NHEAD + n) * SEQ + s];
        const float mean = (hv.x + hv.y + hv.z + hv.w) * 0.25f;
        const float d0 = hv.x - mean, d1 = hv.y - mean, d2 = hv.z - mean, d3 = hv.w - mean;
        const float var = (d0 * d0 + d1 * d1 + d2 * d2 + d3 * d3) * 0.25f;
        const float rstd = rsqrtf(var + EPSV);
        const float he = (o == 0) ? hv.x : (o == 1) ? hv.y : (o == 2) ? hv.z : hv.w;
        const float hn = (he - mean) * rstd * on_g[c] + on_b[c];
        const float hk = hn + skip[c] * xc[(size_t)pos * INNER + c];
        hs[p][c] = hk * silu_f(zz[(size_t)pos * INNER + c]);
    }
    __syncthreads();

    const int lane = t & 7, oi = t >> 3;       // oi in [0,64)
    const int p2 = oi & 3, cg = oi >> 2;       // 4 pos x 16 channel-groups
    const int pos = p0 + p2, s = pos % SEQ;
    const float4* hr = (const float4*)(&hs[p2][0]) + lane * 6;
    float4 h4[6];
    #pragma unroll
    for (int j = 0; j < 6; ++j) h4[j] = hr[j];
    #pragma unroll
    for (int j = 0; j < 6; ++j) {
        const int c = cg + 16 * j;             // 0..95
        const float4* wr = (const float4*)(w_down + (size_t)c * INNER) + lane * 6;
        float acc = 0.f;
        #pragma unroll
        for (int u = 0; u < 6; ++u) {
            const float4 w = wr[u];
            acc += h4[u].x * w.x + h4[u].y * w.y + h4[u].z * w.z + h4[u].w * w.w;
        }
        #pragma unroll
        for (int off = 1; off < 8; off <<= 1) acc += __shfl_xor(acc, off);
        if (lane == 0) {
            const size_t idx = ((size_t)b * CDIM + c) * SEQ + s;
            out[idx] = x[idx] + acc + b_down[c];
        }
    }
}

extern "C" void kernel_launch(void* const* d_in, const int* in_sizes, int n_in,
                              void* d_out, int out_size, void* d_ws, size_t ws_size,
                              hipStream_t stream) {
    const float* x      = (const float*)d_in[0];
    const float* ln_g   = (const float*)d_in[1];
    const float* ln_b   = (const float*)d_in[2];
    const float* w_up   = (const float*)d_in[3];
    const float* b_up   = (const float*)d_in[4];
    const float* w_q    = (const float*)d_in[5];
    const float* b_q    = (const float*)d_in[6];
    const float* w_k    = (const float*)d_in[7];
    const float* b_k    = (const float*)d_in[8];
    const float* w_v    = (const float*)d_in[9];
    const float* b_v    = (const float*)d_in[10];
    const float* w_conv = (const float*)d_in[11];
    const float* b_conv = (const float*)d_in[12];
    const float* w_ig   = (const float*)d_in[13];
    const float* b_ig   = (const float*)d_in[14];
    const float* w_fg   = (const float*)d_in[15];
    const float* b_fg   = (const float*)d_in[16];
    const float* on_g   = (const float*)d_in[17];
    const float* on_b   = (const float*)d_in[18];
    const float* skip   = (const float*)d_in[19];
    const float* w_down = (const float*)d_in[20];
    const float* b_down = (const float*)d_in[21];

    float* ws = (float*)d_ws;
    const size_t NSI = (size_t)NB * SEQ * INNER;       // 221184
    const size_t NHS = (size_t)NB * NHEAD * SEQ;       // 55296
    float* xm  = ws;                // x_mlstm [B*S][192]
    float* z   = xm + NSI;
    float* xc  = z + NSI;
    float* qw  = xc + NSI;          // head-major [B][NH][S][4]
    float* kw  = qw + NSI;
    float* vw  = kw + NSI;
    float* igw = vw + NSI;          // [B][NH][S]
    float* fgw = igw + NHS;
    float* ht  = fgw + NHS;         // [B][NH][S][4]

    float* out = (float*)d_out;

    hipLaunchKernelGGL(k_ln_up, dim3(NB * SEQ / 8, 2), dim3(512), 0, stream,
                       x, ln_g, ln_b, w_up, b_up, xm, z);
    hipLaunchKernelGGL(k_conv_qkv_gates, dim3(NB * SEQ / 4), dim3(512), 0, stream,
                       xm, w_conv, b_conv, w_q, b_q, w_k, b_k, w_v, b_v,
                       w_ig, b_ig, w_fg, b_fg, xc, qw, kw, vw, igw, fgw);
    hipLaunchKernelGGL(k_mlstm, dim3(NB * NHEAD, SEQ / RT), dim3(256), 0, stream,
                       qw, kw, vw, igw, fgw, ht);
    hipLaunchKernelGGL(k_epi, dim3(NB * SEQ / 4), dim3(512), 0, stream,
                       ht, on_g, on_b, skip, xc, z, w_down, b_down, x, out);
}